// Round 1
// baseline (2874.728 us; speedup 1.0000x reference)
//
#include <hip/hip_runtime.h>
#include <math.h>

#define T_SEQ  8192
#define EMBED  27
#define HIDDEN 30
#define GATES  (4 * HIDDEN)   // 120

// sigmoid(x) = 1/(1+2^(-x*log2 e)) via hw exp2 + rcp + 1 Newton step.
// Clamp exp2 arg to avoid inf -> inf*0 NaN in the NR step (pre-activations
// here are bounded ~|15|, so clamp never triggers in practice).
__device__ __forceinline__ float sig_fast(float x) {
    float a = fminf(-1.44269504088896340736f * x, 80.0f);
    float e = exp2f(a);
    float d = 1.0f + e;
    float r = __builtin_amdgcn_rcpf(d);
    r = r * (2.0f - d * r);   // Newton refine: ~1 ulp
    return r;
}

// ---------------- Phase 1: gx[t][j] = emb[tok[t]] . W_ih[j] + b_ih[j] + b_hh[j]
__global__ __launch_bounds__(128) void gx_kernel(
        const int* __restrict__ tokens, const float* __restrict__ emb,
        const float* __restrict__ W_ih, const float* __restrict__ b_ih,
        const float* __restrict__ b_hh, float* __restrict__ gx) {
    const int t = blockIdx.x;
    const int j = threadIdx.x;
    __shared__ float x[EMBED];
    const int tok = tokens[t];
    if (j < EMBED) x[j] = emb[(size_t)tok * EMBED + j];
    __syncthreads();
    if (j < GATES) {
        float acc = b_ih[j] + b_hh[j];
        #pragma unroll
        for (int e = 0; e < EMBED; ++e)
            acc = fmaf(x[e], W_ih[j * EMBED + e], acc);
        gx[t * GATES + j] = acc;
    }
}

// ---------------- Phase 2: serial LSTM scan, single wave.
// Lane map: half0 lane k -> rows i[k] (k), g[k] (60+k)
//           half1 lane k -> rows f[k] (30+k), o[k] (90+k)
// h broadcast: 30x v_readlane into SGPRs; gate exchange: 2x shfl_xor(32).
__global__ __launch_bounds__(64) void scan_kernel(
        const float* __restrict__ gx, const float* __restrict__ W_hh,
        const float* __restrict__ W_lin, const float* __restrict__ b_lin,
        float* __restrict__ out) {
    const int lane = threadIdx.x;
    const int half = lane >> 5;
    const int k    = lane & 31;
    const int kk   = (k < HIDDEN) ? k : 0;          // clamp idle lanes to valid rows
    const int row_a = (half == 0) ? kk              : HIDDEN + kk;       // i | f
    const int row_b = (half == 0) ? 2 * HIDDEN + kk : 3 * HIDDEN + kk;   // g | o

    float wa[HIDDEN], wb[HIDDEN];
    #pragma unroll
    for (int j = 0; j < HIDDEN; ++j) {
        wa[j] = W_hh[row_a * HIDDEN + j];
        wb[j] = W_hh[row_b * HIDDEN + j];
    }

    float hb[HIDDEN];
    #pragma unroll
    for (int j = 0; j < HIDDEN; ++j) hb[j] = 0.0f;
    float c = 0.0f;

    float ga = gx[row_a];
    float gb = gx[row_b];

    for (int t = 0; t < T_SEQ; ++t) {
        float acc_a = ga;
        float acc_b = gb;
        // prefetch next step's gx (hidden under this step's compute)
        const int tn = (t + 1 < T_SEQ) ? t + 1 : t;
        ga = gx[tn * GATES + row_a];
        gb = gx[tn * GATES + row_b];

        #pragma unroll
        for (int j = 0; j < HIDDEN; ++j) {
            acc_a = fmaf(hb[j], wa[j], acc_a);
            acc_b = fmaf(hb[j], wb[j], acc_b);
        }

        // acc_a: sigmoid on both halves (i | f).
        // acc_b: tanh on half0 (g), sigmoid on half1 (o) — branchless via
        // tanh(x) = 2*sigmoid(2x) - 1.
        float va = sig_fast(acc_a);
        float xb = (half == 0) ? acc_b * 2.0f : acc_b;
        float sb = sig_fast(xb);
        float vb = (half == 0) ? fmaf(2.0f, sb, -1.0f) : sb;

        float sf = __shfl_xor(va, 32, 64);   // half0 lane k <- sigmoid(f[k])
        float so = __shfl_xor(vb, 32, 64);   // half0 lane k <- sigmoid(o[k])

        // c/h update (meaningful on half0 lanes k<30; harmless elsewhere)
        float cn = fmaf(sf, c, va * vb);     // f*c + i*tanh(g)
        c = cn;
        // tanh(cn) = 2*sigmoid(2*cn) - 1
        float a2 = fminf(-2.88539008177792681472f * cn, 80.0f);
        float e2 = exp2f(a2);
        float d2 = 1.0f + e2;
        float r2 = __builtin_amdgcn_rcpf(d2);
        r2 = r2 * (2.0f - d2 * r2);
        float tc = fmaf(2.0f, r2, -1.0f);
        float hn = so * tc;

        // broadcast new h to all lanes as wave-uniform (SGPR) values
        #pragma unroll
        for (int j = 0; j < HIDDEN; ++j)
            hb[j] = __uint_as_float(
                (unsigned)__builtin_amdgcn_readlane(__float_as_uint(hn), j));
    }

    if (lane == 0) {
        float s = b_lin[0];
        #pragma unroll
        for (int j = 0; j < HIDDEN; ++j) s = fmaf(hb[j], W_lin[j], s);
        out[0] = s;
    }
}

// ---------------- Fallback: fused scan computing gx on the fly (if ws too small)
__global__ __launch_bounds__(64) void scan_fused(
        const int* __restrict__ tokens, const float* __restrict__ emb,
        const float* __restrict__ W_ih, const float* __restrict__ b_ih,
        const float* __restrict__ b_hh, const float* __restrict__ W_hh,
        const float* __restrict__ W_lin, const float* __restrict__ b_lin,
        float* __restrict__ out) {
    const int lane = threadIdx.x;
    const int half = lane >> 5;
    const int k    = lane & 31;
    const int kk   = (k < HIDDEN) ? k : 0;
    const int row_a = (half == 0) ? kk              : HIDDEN + kk;
    const int row_b = (half == 0) ? 2 * HIDDEN + kk : 3 * HIDDEN + kk;

    float wa[HIDDEN], wb[HIDDEN];
    #pragma unroll
    for (int j = 0; j < HIDDEN; ++j) {
        wa[j] = W_hh[row_a * HIDDEN + j];
        wb[j] = W_hh[row_b * HIDDEN + j];
    }
    float wia[EMBED], wib[EMBED];
    #pragma unroll
    for (int e = 0; e < EMBED; ++e) {
        wia[e] = W_ih[row_a * EMBED + e];
        wib[e] = W_ih[row_b * EMBED + e];
    }
    const float bias_a = b_ih[row_a] + b_hh[row_a];
    const float bias_b = b_ih[row_b] + b_hh[row_b];

    float hb[HIDDEN];
    #pragma unroll
    for (int j = 0; j < HIDDEN; ++j) hb[j] = 0.0f;
    float c = 0.0f;

    for (int t = 0; t < T_SEQ; ++t) {
        const int tok = tokens[t];
        float x[EMBED];
        #pragma unroll
        for (int e = 0; e < EMBED; ++e) x[e] = emb[(size_t)tok * EMBED + e];

        float acc_a = bias_a;
        float acc_b = bias_b;
        #pragma unroll
        for (int e = 0; e < EMBED; ++e) {
            acc_a = fmaf(x[e], wia[e], acc_a);
            acc_b = fmaf(x[e], wib[e], acc_b);
        }
        #pragma unroll
        for (int j = 0; j < HIDDEN; ++j) {
            acc_a = fmaf(hb[j], wa[j], acc_a);
            acc_b = fmaf(hb[j], wb[j], acc_b);
        }

        float va = sig_fast(acc_a);
        float xb = (half == 0) ? acc_b * 2.0f : acc_b;
        float sb = sig_fast(xb);
        float vb = (half == 0) ? fmaf(2.0f, sb, -1.0f) : sb;

        float sf = __shfl_xor(va, 32, 64);
        float so = __shfl_xor(vb, 32, 64);

        float cn = fmaf(sf, c, va * vb);
        c = cn;
        float a2 = fminf(-2.88539008177792681472f * cn, 80.0f);
        float e2 = exp2f(a2);
        float d2 = 1.0f + e2;
        float r2 = __builtin_amdgcn_rcpf(d2);
        r2 = r2 * (2.0f - d2 * r2);
        float tc = fmaf(2.0f, r2, -1.0f);
        float hn = so * tc;

        #pragma unroll
        for (int j = 0; j < HIDDEN; ++j)
            hb[j] = __uint_as_float(
                (unsigned)__builtin_amdgcn_readlane(__float_as_uint(hn), j));
    }

    if (lane == 0) {
        float s = b_lin[0];
        #pragma unroll
        for (int j = 0; j < HIDDEN; ++j) s = fmaf(hb[j], W_lin[j], s);
        out[0] = s;
    }
}

extern "C" void kernel_launch(void* const* d_in, const int* in_sizes, int n_in,
                              void* d_out, int out_size, void* d_ws, size_t ws_size,
                              hipStream_t stream) {
    const int*   tokens = (const int*)d_in[0];
    const float* emb    = (const float*)d_in[1];
    const float* W_ih   = (const float*)d_in[2];
    const float* W_hh   = (const float*)d_in[3];
    const float* b_ih   = (const float*)d_in[4];
    const float* b_hh   = (const float*)d_in[5];
    const float* W_lin  = (const float*)d_in[6];
    const float* b_lin  = (const float*)d_in[7];
    float* out = (float*)d_out;

    const size_t need = (size_t)T_SEQ * GATES * sizeof(float);  // 3.93 MB
    if (ws_size >= need) {
        float* gx = (float*)d_ws;
        gx_kernel<<<T_SEQ, 128, 0, stream>>>(tokens, emb, W_ih, b_ih, b_hh, gx);
        scan_kernel<<<1, 64, 0, stream>>>(gx, W_hh, W_lin, b_lin, out);
    } else {
        scan_fused<<<1, 64, 0, stream>>>(tokens, emb, W_ih, b_ih, b_hh,
                                         W_hh, W_lin, b_lin, out);
    }
}